// Round 6
// baseline (536.374 us; speedup 1.0000x reference)
//
#include <hip/hip_runtime.h>
#include <hip/hip_bf16.h>

typedef float f32x4 __attribute__((ext_vector_type(4)));
typedef int v8i __attribute__((ext_vector_type(8)));

#define AS3 __attribute__((address_space(3)))
#define AS1 __attribute__((address_space(1)))

// ---------------- fp32 -> fp8 e4m3 (OCP) conversion with x16 scale (q and t fused) ----------------
__global__ __launch_bounds__(256) void cvt_fp8_kernel(const float* __restrict__ q,
                                                      const float* __restrict__ t,
                                                      unsigned int* __restrict__ qd,
                                                      unsigned int* __restrict__ td,
                                                      int n16) {
  int idx = blockIdx.x * 256 + threadIdx.x;
  const float* src;
  unsigned int* dst;
  if (idx < n16) { src = q; dst = qd; }
  else           { idx -= n16; if (idx >= n16) return; src = t; dst = td; }
  const float4* s4 = (const float4*)src;
  uint4 o;
  unsigned int* op = (unsigned int*)&o;
#pragma unroll
  for (int i = 0; i < 4; ++i) {
    float4 v = s4[idx * 4 + i];
    int w = 0;
    w = __builtin_amdgcn_cvt_pk_fp8_f32(v.x * 16.f, v.y * 16.f, w, false);
    w = __builtin_amdgcn_cvt_pk_fp8_f32(v.z * 16.f, v.w * 16.f, w, true);
    op[i] = w;
  }
  ((uint4*)dst)[idx] = o;
}

// ---------------- fused GEMM (MX fp8, K=128) + max over p -> Cmax[4608][512] ----------------
// 288x288 tile, 1D grid 256 with XCD-aware swizzle (XCD=blk%8 gets a 4bi x 8bj rectangle
// -> A panels read by 2 XCDs, B by 4: ~106 MB LLC traffic vs 566 naive).
// 768 thr = 12 waves (6x2), wave tile 48x144. BK=128B, 30 iters, double-buffered LDS.
// LDS layout k-chunk-major: A[kc][row] 16B units (kc<8), B likewise @36864 -> contiguous
// staging (slot s -> addr s*16) and contiguous b128 frag reads, no swizzle math.
__global__ __launch_bounds__(768) void gemm_cmax_kernel(const unsigned char* __restrict__ qf8,
                                                        const unsigned char* __restrict__ tf8,
                                                        float* __restrict__ cmax) {
  __shared__ __align__(16) char smem[147456];
  const int tid  = threadIdx.x;
  const int wv   = tid >> 6;
  const int lane = tid & 63;
  const int quad = lane >> 4;
  const int l16  = lane & 15;
  const int wrow = wv >> 1, wcol = wv & 1;
  // XCD swizzle: x = blk%8 -> (bi-group, bj-group)
  const int x = blockIdx.x & 7, r = blockIdx.x >> 3;
  const int bi = (x >> 1) * 4 + (r & 3);
  const int bj = (x & 1) * 8 + (r >> 2);

  f32x4 acc[3][9];
#pragma unroll
  for (int a = 0; a < 3; ++a)
#pragma unroll
    for (int b = 0; b < 9; ++b) acc[a][b] = (f32x4){0.f, 0.f, 0.f, 0.f};

  // staging: slot s in [0,4608): A = s<2304 (kc=s/288, row=s%288), B else. LDS dest = s*16.
  const unsigned char* gptr[6];
  int ldst[6];
#pragma unroll
  for (int i = 0; i < 6; ++i) {
    int s   = i * 768 + tid;
    int mat = (s >= 2304);
    int sm  = s - mat * 2304;
    int kc  = sm / 288, row = sm % 288;
    const unsigned char* base = mat ? (tf8 + (size_t)(bj * 288 + row) * 3840)
                                    : (qf8 + (size_t)(bi * 288 + row) * 3840);
    gptr[i] = base + kc * 16;
    ldst[i] = s * 16;
  }

  int buf = 0;
#pragma unroll
  for (int i = 0; i < 6; ++i)
    __builtin_amdgcn_global_load_lds((const AS1 void*)(gptr[i]),
                                     (AS3 void*)(smem + ldst[i]), 16, 0, 0);

  const int arow = wrow * 48 + l16;
  const int bcol = wcol * 144 + l16;

  for (int kt = 0; kt < 30; ++kt) {
    __syncthreads();  // drains vmcnt(0): current buf staged; prev buf reads done
    if (kt < 29) {
      int nb = buf ^ 1;
#pragma unroll
      for (int i = 0; i < 6; ++i)
        __builtin_amdgcn_global_load_lds((const AS1 void*)(gptr[i] + (kt + 1) * 128),
                                         (AS3 void*)(smem + nb * 73728 + ldst[i]), 16, 0, 0);
    }
    const char* A = smem + buf * 73728;
    const char* B = A + 36864;

    v8i av[3];
#pragma unroll
    for (int sr = 0; sr < 3; ++sr) {
      int rr = arow + sr * 16;
      int4 lo = *(const int4*)(A + ((quad * 2) * 288 + rr) * 16);
      int4 hi = *(const int4*)(A + ((quad * 2 + 1) * 288 + rr) * 16);
      v8i v;
      v[0] = lo.x; v[1] = lo.y; v[2] = lo.z; v[3] = lo.w;
      v[4] = hi.x; v[5] = hi.y; v[6] = hi.z; v[7] = hi.w;
      av[sr] = v;
    }
#pragma unroll
    for (int c = 0; c < 9; ++c) {
      int cc = bcol + c * 16;
      int4 lo = *(const int4*)(B + ((quad * 2) * 288 + cc) * 16);
      int4 hi = *(const int4*)(B + ((quad * 2 + 1) * 288 + cc) * 16);
      v8i bv;
      bv[0] = lo.x; bv[1] = lo.y; bv[2] = lo.z; bv[3] = lo.w;
      bv[4] = hi.x; bv[5] = hi.y; bv[6] = hi.z; bv[7] = hi.w;
      acc[0][c] = __builtin_amdgcn_mfma_scale_f32_16x16x128_f8f6f4(
          av[0], bv, acc[0][c], 0, 0, 0, 0x7f7f7f7f, 0, 0x7f7f7f7f);
      acc[1][c] = __builtin_amdgcn_mfma_scale_f32_16x16x128_f8f6f4(
          av[1], bv, acc[1][c], 0, 0, 0, 0x7f7f7f7f, 0, 0x7f7f7f7f);
      acc[2][c] = __builtin_amdgcn_mfma_scale_f32_16x16x128_f8f6f4(
          av[2], bv, acc[2][c], 0, 0, 0, 0x7f7f7f7f, 0, 0x7f7f7f7f);
    }
    buf ^= 1;
  }

  // -------- epilogue: 18 bands of 16 rows; rowmax over each 9-col group --------
  __syncthreads();
  float* scr = (float*)smem;  // [16][288]
#pragma unroll
  for (int b = 0; b < 18; ++b) {
    const int bw = b / 3, bs = b - bw * 3;
    if (wrow == bw) {
#pragma unroll
      for (int c = 0; c < 9; ++c)
#pragma unroll
        for (int rr = 0; rr < 4; ++rr)
          scr[(quad * 4 + rr) * 288 + wcol * 144 + c * 16 + l16] = acc[bs][c][rr] * (1.f / 256.f);
    }
    __syncthreads();
    if (tid < 512) {
      int row = tid >> 5, jg = tid & 31;
      const float* p = scr + row * 288 + jg * 9;
      float m = p[0];
#pragma unroll
      for (int k = 1; k < 9; ++k) m = fmaxf(m, p[k]);
      cmax[(size_t)(bi * 288 + b * 16 + row) * 512 + bj * 32 + jg] = m;
    }
    __syncthreads();
  }
}

// ---------------- mean over o (9 rows) -> f2f[512][512] ----------------
__global__ __launch_bounds__(512) void mean9_kernel(const float* __restrict__ cmax,
                                                    float* __restrict__ f2f) {
  int i = blockIdx.x, j = threadIdx.x;
  float s = 0.f;
#pragma unroll
  for (int o = 0; o < 9; ++o) s += cmax[(size_t)(i * 9 + o) * 512 + j];
  f2f[i * 512 + j] = s * (1.f / 9.f);
}

// ---------------- conv1: 1->32ch 3x3 same + relu + 2x2 maxpool, 512^2 -> 256^2 ----------------
__global__ __launch_bounds__(256) void conv1_kernel(const float* __restrict__ in,
                                                    const float* __restrict__ w1,
                                                    const float* __restrict__ b1,
                                                    float* __restrict__ out) {
  __shared__ float tile[34 * 36];
  __shared__ float wl[320];
  int t = blockIdx.x;
  int ty0 = (t >> 4) * 32, tx0 = (t & 15) * 32;
  int py = threadIdx.x >> 4, px = threadIdx.x & 15;

  for (int idx = threadIdx.x; idx < 320; idx += 256)
    wl[idx] = (idx < 288) ? w1[idx] : b1[idx - 288];
  for (int idx = threadIdx.x; idx < 34 * 34; idx += 256) {
    int r = idx / 34, c = idx % 34;
    int gy = ty0 + r - 1, gx = tx0 + c - 1;
    tile[r * 36 + c] = ((unsigned)gy < 512u && (unsigned)gx < 512u) ? in[gy * 512 + gx] : 0.f;
  }
  __syncthreads();

  float win[4][4];
#pragma unroll
  for (int r = 0; r < 4; ++r)
#pragma unroll
    for (int c = 0; c < 4; ++c)
      win[r][c] = tile[(2 * py + r) * 36 + 2 * px + c];

  int gy2 = (t >> 4) * 16 + py, gx2 = (t & 15) * 16 + px;
#pragma unroll 1
  for (int ch = 0; ch < 32; ++ch) {
    float w[9];
#pragma unroll
    for (int k = 0; k < 9; ++k) w[k] = wl[ch * 9 + k];
    float m = -INFINITY;
#pragma unroll
    for (int a = 0; a < 2; ++a)
#pragma unroll
      for (int b = 0; b < 2; ++b) {
        float s = 0.f;
#pragma unroll
        for (int ky = 0; ky < 3; ++ky)
#pragma unroll
          for (int kx = 0; kx < 3; ++kx) s += win[a + ky][b + kx] * w[ky * 3 + kx];
        m = fmaxf(m, s);
      }
    out[ch * 65536 + gy2 * 256 + gx2] = fmaxf(m + wl[288 + ch], 0.f);
  }
}

// ---------------- conv2: 32->64ch 3x3 same + relu + 2x2 maxpool, 256^2 -> 128^2 ----------------
// 8 co/block, 512 blocks. Hoisted staging addresses (no per-round div/mod),
// double-buffered input (2 ci planes/round), weights in LDS.
__global__ __launch_bounds__(256) void conv2_kernel(const float* __restrict__ in,
                                                    const float* __restrict__ w2,
                                                    const float* __restrict__ b2,
                                                    float* __restrict__ out) {
  __shared__ __align__(16) float wlds[32 * 8 * 12];   // 12288 B
  __shared__ float tile[2 * 2448];                    // [buf][pl*1224 + r*36 + c] 19584 B
  const int tid = threadIdx.x;
  int cog = blockIdx.x >> 6;          // 0..7 -> 8 output channels
  int t   = blockIdx.x & 63;          // 8x8 tiles of 32x32 pre-pool
  int ty0 = (t >> 3) * 32, tx0 = (t & 7) * 32;
  int py = tid >> 4, px = tid & 15;

  for (int idx = tid; idx < 2304; idx += 256) {
    int co = idx / 288, rem = idx % 288, ci = rem / 9, k = rem % 9;
    wlds[(ci * 8 + co) * 12 + k] = w2[((cog * 8 + co) * 32 + ci) * 9 + k];
  }
  // hoisted halo decode: 2 planes x 34x34 = 2312 elems, 10 slots
  int goffs[10], loffs[10];
#pragma unroll
  for (int i = 0; i < 10; ++i) {
    int idx = tid + i * 256;
    if (idx < 2312) {
      int pl = idx / 1156, rc = idx % 1156, rr = rc / 34, cc = rc % 34;
      loffs[i] = pl * 1224 + rr * 36 + cc;
      int gy = ty0 + rr - 1, gx = tx0 + cc - 1;
      goffs[i] = ((unsigned)gy < 256u && (unsigned)gx < 256u) ? pl * 65536 + gy * 256 + gx : -1;
    } else { loffs[i] = -1; goffs[i] = -1; }
  }
#pragma unroll
  for (int i = 0; i < 10; ++i)
    if (loffs[i] >= 0) tile[loffs[i]] = (goffs[i] >= 0) ? in[goffs[i]] : 0.f;
  __syncthreads();

  float acc[4][8];
#pragma unroll
  for (int p = 0; p < 4; ++p)
#pragma unroll
    for (int co = 0; co < 8; ++co) acc[p][co] = 0.f;

#pragma unroll 1
  for (int cb = 0; cb < 16; ++cb) {
    int buf = cb & 1;
    float pf[10];
    if (cb < 15) {
#pragma unroll
      for (int i = 0; i < 10; ++i)
        pf[i] = (goffs[i] >= 0) ? in[goffs[i] + (cb + 1) * 131072] : 0.f;
    }
    const float* tb = tile + buf * 2448;
#pragma unroll
    for (int pl = 0; pl < 2; ++pl) {
      float win[4][4];
#pragma unroll
      for (int rr = 0; rr < 4; ++rr) {
        float2 lo = *(const float2*)&tb[pl * 1224 + (2 * py + rr) * 36 + 2 * px];
        float2 hi = *(const float2*)&tb[pl * 1224 + (2 * py + rr) * 36 + 2 * px + 2];
        win[rr][0] = lo.x; win[rr][1] = lo.y; win[rr][2] = hi.x; win[rr][3] = hi.y;
      }
      int ci = cb * 2 + pl;
#pragma unroll
      for (int co = 0; co < 8; ++co) {
        const float* wp = &wlds[(ci * 8 + co) * 12];
        float4 w0 = *(const float4*)wp;
        float4 w1v = *(const float4*)(wp + 4);
        float w8 = wp[8];
        float w[9] = {w0.x, w0.y, w0.z, w0.w, w1v.x, w1v.y, w1v.z, w1v.w, w8};
#pragma unroll
        for (int a = 0; a < 2; ++a)
#pragma unroll
          for (int b = 0; b < 2; ++b) {
            float s = acc[a * 2 + b][co];
#pragma unroll
            for (int ky = 0; ky < 3; ++ky)
#pragma unroll
              for (int kx = 0; kx < 3; ++kx) s += win[a + ky][b + kx] * w[ky * 3 + kx];
            acc[a * 2 + b][co] = s;
          }
      }
    }
    if (cb < 15) {
#pragma unroll
      for (int i = 0; i < 10; ++i)
        if (loffs[i] >= 0) tile[(buf ^ 1) * 2448 + loffs[i]] = pf[i];
    }
    __syncthreads();
  }

  int gy2 = (t >> 3) * 16 + py, gx2 = (t & 7) * 16 + px;
#pragma unroll
  for (int co = 0; co < 8; ++co) {
    float m = fmaxf(fmaxf(acc[0][co], acc[1][co]), fmaxf(acc[2][co], acc[3][co]));
    out[(cog * 8 + co) * 16384 + gy2 * 128 + gx2] = fmaxf(m + b2[cog * 8 + co], 0.f);
  }
}

// ---------------- conv3: 64->128ch 3x3 same + relu, 128^2 ----------------
// 16x32 tile, 2 px/thread, 8 co/block -> 512 blocks (3 blocks/CU). Hoisted staging
// addresses, 4 ci planes/round double-buffered, weights in LDS.
__global__ __launch_bounds__(256) void conv3_kernel(const float* __restrict__ in,
                                                    const float* __restrict__ w3,
                                                    const float* __restrict__ b3,
                                                    float* __restrict__ out) {
  __shared__ __align__(16) float wlds[64 * 8 * 12];   // 24576 B
  __shared__ float tile[2 * 2520];                    // [buf][pl*630 + r*35 + c] 20160 B
  const int tid = threadIdx.x;
  int cog = blockIdx.x >> 5;          // 0..15 -> 8 output channels
  int t   = blockIdx.x & 31;          // 8 (y) x 4 (x) tiles of 16x32
  int ty0 = (t >> 2) * 16, tx0 = (t & 3) * 32;
  int py = tid >> 4, px = tid & 15;   // pixels (py, px) and (py, px+16)

  for (int idx = tid; idx < 4608; idx += 256) {
    int co = idx / 576, rem = idx % 576, ci = rem / 9, k = rem % 9;
    wlds[(ci * 8 + co) * 12 + k] = w3[((cog * 8 + co) * 64 + ci) * 9 + k];
  }
  // hoisted halo decode: 4 planes x 18x34 = 2448 elems, 10 slots
  int goffs[10], loffs[10];
#pragma unroll
  for (int i = 0; i < 10; ++i) {
    int idx = tid + i * 256;
    if (idx < 2448) {
      int pl = idx / 612, rc = idx % 612, rr = rc / 34, cc = rc % 34;
      loffs[i] = pl * 630 + rr * 35 + cc;
      int gy = ty0 + rr - 1, gx = tx0 + cc - 1;
      goffs[i] = ((unsigned)gy < 128u && (unsigned)gx < 128u) ? pl * 16384 + gy * 128 + gx : -1;
    } else { loffs[i] = -1; goffs[i] = -1; }
  }
#pragma unroll
  for (int i = 0; i < 10; ++i)
    if (loffs[i] >= 0) tile[loffs[i]] = (goffs[i] >= 0) ? in[goffs[i]] : 0.f;
  __syncthreads();

  float acc0[8], acc1[8];
#pragma unroll
  for (int co = 0; co < 8; ++co) { acc0[co] = 0.f; acc1[co] = 0.f; }

#pragma unroll 1
  for (int cb = 0; cb < 16; ++cb) {
    int buf = cb & 1;
    float pf[10];
    if (cb < 15) {
#pragma unroll
      for (int i = 0; i < 10; ++i)
        pf[i] = (goffs[i] >= 0) ? in[goffs[i] + (cb + 1) * 65536] : 0.f;
    }
    const float* tb = tile + buf * 2520;
#pragma unroll
    for (int pl = 0; pl < 4; ++pl) {
      float wn[3][6];
#pragma unroll
      for (int rr = 0; rr < 3; ++rr)
#pragma unroll
        for (int cc = 0; cc < 3; ++cc) {
          wn[rr][cc]     = tb[pl * 630 + (py + rr) * 35 + px + cc];
          wn[rr][3 + cc] = tb[pl * 630 + (py + rr) * 35 + px + 16 + cc];
        }
      int ci = cb * 4 + pl;
#pragma unroll
      for (int co = 0; co < 8; ++co) {
        const float* wp = &wlds[(ci * 8 + co) * 12];
        float4 w0 = *(const float4*)wp;
        float4 w1v = *(const float4*)(wp + 4);
        float w8 = wp[8];
        float w[9] = {w0.x, w0.y, w0.z, w0.w, w1v.x, w1v.y, w1v.z, w1v.w, w8};
        float s0 = acc0[co], s1 = acc1[co];
#pragma unroll
        for (int ky = 0; ky < 3; ++ky)
#pragma unroll
          for (int kx = 0; kx < 3; ++kx) {
            s0 += wn[ky][kx] * w[ky * 3 + kx];
            s1 += wn[ky][3 + kx] * w[ky * 3 + kx];
          }
        acc0[co] = s0; acc1[co] = s1;
      }
    }
    if (cb < 15) {
#pragma unroll
      for (int i = 0; i < 10; ++i)
        if (loffs[i] >= 0) tile[(buf ^ 1) * 2520 + loffs[i]] = pf[i];
    }
    __syncthreads();
  }

  int y = ty0 + py;
#pragma unroll
  for (int co = 0; co < 8; ++co) {
    float bias = b3[cog * 8 + co];
    float* op = out + (cog * 8 + co) * 16384 + y * 128 + tx0 + px;
    op[0]  = fmaxf(acc0[co] + bias, 0.f);
    op[16] = fmaxf(acc1[co] + bias, 0.f);
  }
}

// ---------------- 1x1 conv (128->1) + bias + clip + rowmax over x ----------------
__global__ __launch_bounds__(512) void convf_kernel(const float* __restrict__ in,
                                                    const float* __restrict__ wf,
                                                    const float* __restrict__ bfp,
                                                    float* __restrict__ rowm) {
  __shared__ float part[512];
  int y = blockIdx.x, tid = threadIdx.x;
  int pt = tid >> 7, x = tid & 127;
  float acc = 0.f;
  const float* ip = in + y * 128 + x;
  for (int ci = pt * 32; ci < pt * 32 + 32; ++ci) acc += ip[ci * 16384] * wf[ci];
  part[tid] = acc;
  __syncthreads();
  if (tid < 128) {
    float s = part[tid] + part[tid + 128] + part[tid + 256] + part[tid + 384] + bfp[0];
    part[tid] = fminf(fmaxf(s, -1.f), 1.f);
  }
  __syncthreads();
  if (tid < 64) {
    float m = fmaxf(part[tid], part[tid + 64]);
    for (int off = 32; off; off >>= 1) m = fmaxf(m, __shfl_down(m, off, 64));
    if (tid == 0) rowm[y] = m;
  }
}

// ---------------- mean over rows -> scalar ----------------
__global__ __launch_bounds__(128) void final_kernel(const float* __restrict__ rowm,
                                                    float* __restrict__ out) {
  int x = threadIdx.x;
  float v = rowm[x];
  for (int off = 32; off; off >>= 1) v += __shfl_down(v, off, 64);
  __shared__ float red[2];
  if ((x & 63) == 0) red[x >> 6] = v;
  __syncthreads();
  if (x == 0) out[0] = (red[0] + red[1]) * (1.f / 128.f);
}

extern "C" void kernel_launch(void* const* d_in, const int* in_sizes, int n_in,
                              void* d_out, int out_size, void* d_ws, size_t ws_size,
                              hipStream_t stream) {
  const float* q  = (const float*)d_in[0];
  const float* t  = (const float*)d_in[1];
  const float* w1 = (const float*)d_in[2];
  const float* b1 = (const float*)d_in[3];
  const float* w2 = (const float*)d_in[4];
  const float* b2 = (const float*)d_in[5];
  const float* w3 = (const float*)d_in[6];
  const float* b3 = (const float*)d_in[7];
  const float* wf = (const float*)d_in[8];
  const float* bf = (const float*)d_in[9];
  float* out = (float*)d_out;
  char* ws = (char*)d_ws;

  unsigned char* qf8 = (unsigned char*)(ws + 0);          // 17,694,720
  unsigned char* tf8 = (unsigned char*)(ws + 17694720);   // 17,694,720
  float* cmax = (float*)(ws + 35389440);                  // 9,437,184
  float* f2f  = (float*)(ws + 44826624);                  // 512x512
  float* x1   = (float*)(ws + 45875200);                  // 32x256x256
  float* x2b  = (float*)(ws + 54263808);                  // 64x128x128
  float* x3   = (float*)(ws + 58458112);                  // 128x128x128
  float* rowm = (float*)(ws + 66846720);                  // 128

  cvt_fp8_kernel<<<8640, 256, 0, stream>>>(q, t, (unsigned int*)qf8, (unsigned int*)tf8, 1105920);
  gemm_cmax_kernel<<<256, 768, 0, stream>>>(qf8, tf8, cmax);
  mean9_kernel<<<512, 512, 0, stream>>>(cmax, f2f);
  conv1_kernel<<<256, 256, 0, stream>>>(f2f, w1, b1, x1);
  conv2_kernel<<<512, 256, 0, stream>>>(x1, w2, b2, x2b);
  conv3_kernel<<<512, 256, 0, stream>>>(x2b, w3, b3, x3);
  convf_kernel<<<128, 512, 0, stream>>>(x3, wf, bf, rowm);
  final_kernel<<<1, 128, 0, stream>>>(rowm, out);
}

// Round 7
// 406.764 us; speedup vs baseline: 1.3186x; 1.3186x over previous
//
#include <hip/hip_runtime.h>
#include <hip/hip_bf16.h>

typedef float f32x4 __attribute__((ext_vector_type(4)));
typedef int v8i __attribute__((ext_vector_type(8)));

#define AS3 __attribute__((address_space(3)))
#define AS1 __attribute__((address_space(1)))

// ---------------- fp32 -> fp8 e4m3 (OCP) conversion with x16 scale (q and t fused) ----------------
__global__ __launch_bounds__(256) void cvt_fp8_kernel(const float* __restrict__ q,
                                                      const float* __restrict__ t,
                                                      unsigned int* __restrict__ qd,
                                                      unsigned int* __restrict__ td,
                                                      int n16) {
  int idx = blockIdx.x * 256 + threadIdx.x;
  const float* src;
  unsigned int* dst;
  if (idx < n16) { src = q; dst = qd; }
  else           { idx -= n16; if (idx >= n16) return; src = t; dst = td; }
  const float4* s4 = (const float4*)src;
  uint4 o;
  unsigned int* op = (unsigned int*)&o;
#pragma unroll
  for (int i = 0; i < 4; ++i) {
    float4 v = s4[idx * 4 + i];
    int w = 0;
    w = __builtin_amdgcn_cvt_pk_fp8_f32(v.x * 16.f, v.y * 16.f, w, false);
    w = __builtin_amdgcn_cvt_pk_fp8_f32(v.z * 16.f, v.w * 16.f, w, true);
    op[i] = w;
  }
  ((uint4*)dst)[idx] = o;
}

// ---------------- fused GEMM (MX fp8, K=128) + max over p -> Cmax[4608][512] ----------------
// R5-proven staging/LDS/frag structure (row-major 16B chunks, XOR ^(row&7)) +
// XCD-aware 1D grid: XCD x = blk%8 gets a 4bi x 8bj rectangle -> per-kt L2 working
// set 442 KB << 4 MB -> staging L2-resident.
__global__ __launch_bounds__(768) void gemm_cmax_kernel(const unsigned char* __restrict__ qf8,
                                                        const unsigned char* __restrict__ tf8,
                                                        float* __restrict__ cmax) {
  __shared__ __align__(16) char smem[147456];
  const int tid  = threadIdx.x;
  const int wv   = tid >> 6;
  const int lane = tid & 63;
  const int quad = lane >> 4;
  const int l16  = lane & 15;
  const int wrow = wv >> 1, wcol = wv & 1;
  const int x = blockIdx.x & 7, r = blockIdx.x >> 3;
  const int bi = (x >> 1) * 4 + (r & 3);
  const int bj = (x & 1) * 8 + (r >> 2);

  f32x4 acc[3][9];
#pragma unroll
  for (int a = 0; a < 3; ++a)
#pragma unroll
    for (int b = 0; b < 9; ++b) acc[a][b] = (f32x4){0.f, 0.f, 0.f, 0.f};

  // staging: slot s in [0,4608): A = s<2304 (row=s>>3, chunk pc=s&7), B else.
  // LDS dest = s*16 (= row*128 + pc*16). Global chunk gc = pc ^ (row&7).
  const unsigned char* gptr[6];
#pragma unroll
  for (int i = 0; i < 6; ++i) {
    int s   = i * 768 + wv * 64 + lane;
    int mat = (s >= 2304);
    int sm  = s - mat * 2304;
    int row = sm >> 3, pc = sm & 7;
    int gc  = pc ^ (row & 7);
    const unsigned char* base = mat ? (tf8 + (size_t)(bj * 288 + row) * 3840)
                                    : (qf8 + (size_t)(bi * 288 + row) * 3840);
    gptr[i] = base + gc * 16;
  }

  int buf = 0;
#pragma unroll
  for (int i = 0; i < 6; ++i)
    __builtin_amdgcn_global_load_lds((const AS1 void*)(gptr[i]),
                                     (AS3 void*)(smem + (i * 768 + wv * 64) * 16), 16, 0, 0);

  const int arow0 = wrow * 48 + l16;
  const int bcol0 = wcol * 144 + l16;

  for (int kt = 0; kt < 30; ++kt) {
    __syncthreads();  // drains vmcnt(0): current buf staged; prev buf reads done
    if (kt < 29) {
      int nb = buf ^ 1;
#pragma unroll
      for (int i = 0; i < 6; ++i)
        __builtin_amdgcn_global_load_lds((const AS1 void*)(gptr[i] + (kt + 1) * 128),
                                         (AS3 void*)(smem + nb * 73728 + (i * 768 + wv * 64) * 16),
                                         16, 0, 0);
    }
    const char* A = smem + buf * 73728;
    const char* B = A + 36864;

    v8i av[3];
#pragma unroll
    for (int sr = 0; sr < 3; ++sr) {
      int row = arow0 + sr * 16;
      int sw  = row & 7;
      int p0  = (quad * 2) ^ sw, p1 = (quad * 2 + 1) ^ sw;
      int4 lo = *(const int4*)(A + row * 128 + p0 * 16);
      int4 hi = *(const int4*)(A + row * 128 + p1 * 16);
      v8i v;
      v[0] = lo.x; v[1] = lo.y; v[2] = lo.z; v[3] = lo.w;
      v[4] = hi.x; v[5] = hi.y; v[6] = hi.z; v[7] = hi.w;
      av[sr] = v;
    }
#pragma unroll
    for (int c = 0; c < 9; ++c) {
      int col = bcol0 + c * 16;
      int sw  = col & 7;
      int p0  = (quad * 2) ^ sw, p1 = (quad * 2 + 1) ^ sw;
      int4 lo = *(const int4*)(B + col * 128 + p0 * 16);
      int4 hi = *(const int4*)(B + col * 128 + p1 * 16);
      v8i bv;
      bv[0] = lo.x; bv[1] = lo.y; bv[2] = lo.z; bv[3] = lo.w;
      bv[4] = hi.x; bv[5] = hi.y; bv[6] = hi.z; bv[7] = hi.w;
      acc[0][c] = __builtin_amdgcn_mfma_scale_f32_16x16x128_f8f6f4(
          av[0], bv, acc[0][c], 0, 0, 0, 0x7f7f7f7f, 0, 0x7f7f7f7f);
      acc[1][c] = __builtin_amdgcn_mfma_scale_f32_16x16x128_f8f6f4(
          av[1], bv, acc[1][c], 0, 0, 0, 0x7f7f7f7f, 0, 0x7f7f7f7f);
      acc[2][c] = __builtin_amdgcn_mfma_scale_f32_16x16x128_f8f6f4(
          av[2], bv, acc[2][c], 0, 0, 0, 0x7f7f7f7f, 0, 0x7f7f7f7f);
    }
    buf ^= 1;
  }

  // -------- epilogue: 18 bands of 16 rows; rowmax over each 9-col group --------
  __syncthreads();
  float* scr = (float*)smem;  // [16][288]
#pragma unroll
  for (int b = 0; b < 18; ++b) {
    const int bw = b / 3, bs = b - bw * 3;
    if (wrow == bw) {
#pragma unroll
      for (int c = 0; c < 9; ++c)
#pragma unroll
        for (int rr = 0; rr < 4; ++rr)
          scr[(quad * 4 + rr) * 288 + wcol * 144 + c * 16 + l16] = acc[bs][c][rr] * (1.f / 256.f);
    }
    __syncthreads();
    if (tid < 512) {
      int row = tid >> 5, jg = tid & 31;
      const float* p = scr + row * 288 + jg * 9;
      float m = p[0];
#pragma unroll
      for (int k = 1; k < 9; ++k) m = fmaxf(m, p[k]);
      cmax[(size_t)(bi * 288 + b * 16 + row) * 512 + bj * 32 + jg] = m;
    }
    __syncthreads();
  }
}

// ---------------- mean over o (9 rows) -> f2f[512][512] ----------------
__global__ __launch_bounds__(512) void mean9_kernel(const float* __restrict__ cmax,
                                                    float* __restrict__ f2f) {
  int i = blockIdx.x, j = threadIdx.x;
  float s = 0.f;
#pragma unroll
  for (int o = 0; o < 9; ++o) s += cmax[(size_t)(i * 9 + o) * 512 + j];
  f2f[i * 512 + j] = s * (1.f / 9.f);
}

// ---------------- conv1: 1->32ch 3x3 same + relu + 2x2 maxpool, 512^2 -> 256^2 ----------------
__global__ __launch_bounds__(256) void conv1_kernel(const float* __restrict__ in,
                                                    const float* __restrict__ w1,
                                                    const float* __restrict__ b1,
                                                    float* __restrict__ out) {
  __shared__ float tile[34 * 36];
  __shared__ float wl[320];
  int t = blockIdx.x;
  int ty0 = (t >> 4) * 32, tx0 = (t & 15) * 32;
  int py = threadIdx.x >> 4, px = threadIdx.x & 15;

  for (int idx = threadIdx.x; idx < 320; idx += 256)
    wl[idx] = (idx < 288) ? w1[idx] : b1[idx - 288];
  for (int idx = threadIdx.x; idx < 34 * 34; idx += 256) {
    int r = idx / 34, c = idx % 34;
    int gy = ty0 + r - 1, gx = tx0 + c - 1;
    tile[r * 36 + c] = ((unsigned)gy < 512u && (unsigned)gx < 512u) ? in[gy * 512 + gx] : 0.f;
  }
  __syncthreads();

  float win[4][4];
#pragma unroll
  for (int r = 0; r < 4; ++r)
#pragma unroll
    for (int c = 0; c < 4; ++c)
      win[r][c] = tile[(2 * py + r) * 36 + 2 * px + c];

  int gy2 = (t >> 4) * 16 + py, gx2 = (t & 15) * 16 + px;
#pragma unroll 1
  for (int ch = 0; ch < 32; ++ch) {
    float w[9];
#pragma unroll
    for (int k = 0; k < 9; ++k) w[k] = wl[ch * 9 + k];
    float m = -INFINITY;
#pragma unroll
    for (int a = 0; a < 2; ++a)
#pragma unroll
      for (int b = 0; b < 2; ++b) {
        float s = 0.f;
#pragma unroll
        for (int ky = 0; ky < 3; ++ky)
#pragma unroll
          for (int kx = 0; kx < 3; ++kx) s += win[a + ky][b + kx] * w[ky * 3 + kx];
        m = fmaxf(m, s);
      }
    out[ch * 65536 + gy2 * 256 + gx2] = fmaxf(m + wl[288 + ch], 0.f);
  }
}

// ---------------- conv2: 32->64ch 3x3 same + relu + 2x2 maxpool, 256^2 -> 128^2 ----------------
// Column-per-thread: thread = col X (0..255), 16 rows, 4 co. Grid 256 = 16 stripes x 16 cog.
// Stride-1 LDS reads (conflict-free), rolling 3-row window, weights reused over 16 rows.
// float4 staging double-buffered (2 planes/round), halo cols always OOB -> zeroed once.
__global__ __launch_bounds__(256) void conv2_kernel(const float* __restrict__ in,
                                                    const float* __restrict__ w2,
                                                    const float* __restrict__ b2,
                                                    float* __restrict__ out) {
  __shared__ __align__(16) float wlds[32 * 4 * 12];   // 6144 B
  __shared__ __align__(16) float tile[2 * 2 * 18 * 264];  // 76032 B; cols at [4+x], halo 3/260
  const int tid = threadIdx.x;
  const int stripe = blockIdx.x & 15, cog = blockIdx.x >> 4;
  const int X = tid;
  const int Y0 = stripe * 16;

  for (int idx = tid; idx < 1152; idx += 256) {
    int co = idx / 288, rem = idx % 288, ci = rem / 9, k = rem % 9;
    wlds[(ci * 4 + co) * 12 + k] = w2[((cog * 4 + co) * 32 + ci) * 9 + k];
  }
  if (tid < 144) {  // zero halo cols: 2buf x 2pl x 18rows x 2sides
    int bu = tid / 72, rem = tid % 72, pl = rem / 36, r2 = rem % 36;
    int rr = r2 >> 1, side = r2 & 1;
    tile[bu * 9504 + pl * 4752 + rr * 264 + (side ? 260 : 3)] = 0.f;
  }
  int gof[9], lof[9];
#pragma unroll
  for (int i = 0; i < 9; ++i) {
    int idx = tid + i * 256;          // < 2304 = 36 rows x 64 f4
    int rw = idx >> 6, c4 = idx & 63;
    int pl = (rw >= 18), rr = rw - pl * 18;
    int gy = Y0 + rr - 1;
    lof[i] = pl * 4752 + rr * 264 + 4 + c4 * 4;
    gof[i] = ((unsigned)gy < 256u) ? (pl * 65536 + gy * 256 + c4 * 4) : -1;
  }
#pragma unroll
  for (int i = 0; i < 9; ++i) {
    float4 v = (gof[i] >= 0) ? *(const float4*)(in + gof[i]) : (float4){0, 0, 0, 0};
    *(float4*)&tile[lof[i]] = v;
  }
  __syncthreads();

  float acc[16][4];
#pragma unroll
  for (int y = 0; y < 16; ++y)
#pragma unroll
    for (int co = 0; co < 4; ++co) acc[y][co] = 0.f;

#pragma unroll 1
  for (int cb = 0; cb < 16; ++cb) {
    int buf = cb & 1;
    float4 pf[9];
    if (cb < 15) {
#pragma unroll
      for (int i = 0; i < 9; ++i)
        pf[i] = (gof[i] >= 0) ? *(const float4*)(in + gof[i] + (cb + 1) * 131072)
                              : (float4){0, 0, 0, 0};
    }
    const float* tb = tile + buf * 9504;
#pragma unroll
    for (int pl = 0; pl < 2; ++pl) {
      const float* tp = tb + pl * 4752;
      int ci = cb * 2 + pl;
      float w[4][9];
#pragma unroll
      for (int co = 0; co < 4; ++co) {
        const float* wp = &wlds[(ci * 4 + co) * 12];
        float4 w0 = *(const float4*)wp;
        float4 w1 = *(const float4*)(wp + 4);
        w[co][0] = w0.x; w[co][1] = w0.y; w[co][2] = w0.z; w[co][3] = w0.w;
        w[co][4] = w1.x; w[co][5] = w1.y; w[co][6] = w1.z; w[co][7] = w1.w;
        w[co][8] = wp[8];
      }
      float r0[3], r1[3], r2[3];
      const float* p0 = tp + X + 3;
      r0[0] = p0[0]; r0[1] = p0[1]; r0[2] = p0[2];
      const float* p1 = tp + 264 + X + 3;
      r1[0] = p1[0]; r1[1] = p1[1]; r1[2] = p1[2];
#pragma unroll
      for (int y = 0; y < 16; ++y) {
        const float* p2 = tp + (y + 2) * 264 + X + 3;
        r2[0] = p2[0]; r2[1] = p2[1]; r2[2] = p2[2];
#pragma unroll
        for (int co = 0; co < 4; ++co)
          acc[y][co] += r0[0] * w[co][0] + r0[1] * w[co][1] + r0[2] * w[co][2]
                      + r1[0] * w[co][3] + r1[1] * w[co][4] + r1[2] * w[co][5]
                      + r2[0] * w[co][6] + r2[1] * w[co][7] + r2[2] * w[co][8];
        r0[0] = r1[0]; r0[1] = r1[1]; r0[2] = r1[2];
        r1[0] = r2[0]; r1[1] = r2[1]; r1[2] = r2[2];
      }
    }
    if (cb < 15) {
#pragma unroll
      for (int i = 0; i < 9; ++i)
        *(float4*)&tile[(buf ^ 1) * 9504 + lof[i]] = pf[i];
    }
    __syncthreads();
  }

  // epilogue: pool rows in-thread, cols via shfl_xor(1); bias+relu
  int x2 = X >> 1;
#pragma unroll
  for (int co = 0; co < 4; ++co) {
    float bias = b2[cog * 4 + co];
#pragma unroll
    for (int y2 = 0; y2 < 8; ++y2) {
      float v = fmaxf(acc[2 * y2][co], acc[2 * y2 + 1][co]);
      v = fmaxf(v + bias, 0.f);
      float o = fmaxf(v, __shfl_xor(v, 1, 64));
      if ((X & 1) == 0)
        out[(cog * 4 + co) * 16384 + (stripe * 8 + y2) * 128 + x2] = o;
    }
  }
}

// ---------------- conv3: 64->128ch 3x3 same + relu, 128^2 ----------------
// Column-per-thread: thread = col X (0..127) x row-half yh, 8 rows, 4 co.
// Grid 256 = 8 stripes x 32 cog. Stride-1 LDS reads, rolling window, f4 staging dbuf.
__global__ __launch_bounds__(256) void conv3_kernel(const float* __restrict__ in,
                                                    const float* __restrict__ w3,
                                                    const float* __restrict__ b3,
                                                    float* __restrict__ out) {
  __shared__ __align__(16) float wlds[64 * 4 * 12];       // 12288 B
  __shared__ __align__(16) float tile[2 * 2 * 18 * 136];  // 39168 B; cols at [4+x], halo 3/132
  const int tid = threadIdx.x;
  const int stripe = blockIdx.x & 7, cog = blockIdx.x >> 3;
  const int X = tid & 127, yh = tid >> 7;   // rows [yh*8, yh*8+8)
  const int Y0 = stripe * 16;

  for (int idx = tid; idx < 2304; idx += 256) {
    int co = idx / 576, rem = idx % 576, ci = rem / 9, k = rem % 9;
    wlds[(ci * 4 + co) * 12 + k] = w3[((cog * 4 + co) * 64 + ci) * 9 + k];
  }
  if (tid < 144) {
    int bu = tid / 72, rem = tid % 72, pl = rem / 36, r2 = rem % 36;
    int rr = r2 >> 1, side = r2 & 1;
    tile[bu * 4896 + pl * 2448 + rr * 136 + (side ? 132 : 3)] = 0.f;
  }
  int gof[5], lof[5];
#pragma unroll
  for (int i = 0; i < 5; ++i) {
    int idx = tid + i * 256;          // < 1152 = 36 rows x 32 f4
    if (idx < 1152) {
      int rw = idx >> 5, c4 = idx & 31;
      int pl = (rw >= 18), rr = rw - pl * 18;
      int gy = Y0 + rr - 1;
      lof[i] = pl * 2448 + rr * 136 + 4 + c4 * 4;
      gof[i] = ((unsigned)gy < 128u) ? (pl * 16384 + gy * 128 + c4 * 4) : -1;
    } else { lof[i] = -1; gof[i] = -1; }
  }
#pragma unroll
  for (int i = 0; i < 5; ++i)
    if (lof[i] >= 0) {
      float4 v = (gof[i] >= 0) ? *(const float4*)(in + gof[i]) : (float4){0, 0, 0, 0};
      *(float4*)&tile[lof[i]] = v;
    }
  __syncthreads();

  float acc[8][4];
#pragma unroll
  for (int y = 0; y < 8; ++y)
#pragma unroll
    for (int co = 0; co < 4; ++co) acc[y][co] = 0.f;

#pragma unroll 1
  for (int cb = 0; cb < 32; ++cb) {
    int buf = cb & 1;
    float4 pf[5];
    if (cb < 31) {
#pragma unroll
      for (int i = 0; i < 5; ++i)
        pf[i] = (gof[i] >= 0) ? *(const float4*)(in + gof[i] + (cb + 1) * 32768)
                              : (float4){0, 0, 0, 0};
    }
    const float* tb = tile + buf * 4896;
#pragma unroll
    for (int pl = 0; pl < 2; ++pl) {
      const float* tp = tb + pl * 2448;
      int ci = cb * 2 + pl;
      float w[4][9];
#pragma unroll
      for (int co = 0; co < 4; ++co) {
        const float* wp = &wlds[(ci * 4 + co) * 12];
        float4 w0 = *(const float4*)wp;
        float4 w1 = *(const float4*)(wp + 4);
        w[co][0] = w0.x; w[co][1] = w0.y; w[co][2] = w0.z; w[co][3] = w0.w;
        w[co][4] = w1.x; w[co][5] = w1.y; w[co][6] = w1.z; w[co][7] = w1.w;
        w[co][8] = wp[8];
      }
      float r0[3], r1[3], r2[3];
      const float* p0 = tp + (yh * 8) * 136 + X + 3;
      r0[0] = p0[0]; r0[1] = p0[1]; r0[2] = p0[2];
      const float* p1 = tp + (yh * 8 + 1) * 136 + X + 3;
      r1[0] = p1[0]; r1[1] = p1[1]; r1[2] = p1[2];
#pragma unroll
      for (int y = 0; y < 8; ++y) {
        const float* p2 = tp + (yh * 8 + y + 2) * 136 + X + 3;
        r2[0] = p2[0]; r2[1] = p2[1]; r2[2] = p2[2];
#pragma unroll
        for (int co = 0; co < 4; ++co)
          acc[y][co] += r0[0] * w[co][0] + r0[1] * w[co][1] + r0[2] * w[co][2]
                      + r1[0] * w[co][3] + r1[1] * w[co][4] + r1[2] * w[co][5]
                      + r2[0] * w[co][6] + r2[1] * w[co][7] + r2[2] * w[co][8];
        r0[0] = r1[0]; r0[1] = r1[1]; r0[2] = r1[2];
        r1[0] = r2[0]; r1[1] = r2[1]; r1[2] = r2[2];
      }
    }
    if (cb < 31) {
#pragma unroll
      for (int i = 0; i < 5; ++i)
        if (lof[i] >= 0) *(float4*)&tile[(buf ^ 1) * 4896 + lof[i]] = pf[i];
    }
    __syncthreads();
  }

#pragma unroll
  for (int co = 0; co < 4; ++co) {
    float bias = b3[cog * 4 + co];
    float* op = out + (cog * 4 + co) * 16384 + (Y0 + yh * 8) * 128 + X;
#pragma unroll
    for (int y = 0; y < 8; ++y)
      op[y * 128] = fmaxf(acc[y][co] + bias, 0.f);
  }
}

// ---------------- 1x1 conv (128->1) + bias + clip + rowmax over x ----------------
__global__ __launch_bounds__(512) void convf_kernel(const float* __restrict__ in,
                                                    const float* __restrict__ wf,
                                                    const float* __restrict__ bfp,
                                                    float* __restrict__ rowm) {
  __shared__ float part[512];
  int y = blockIdx.x, tid = threadIdx.x;
  int pt = tid >> 7, x = tid & 127;
  float acc = 0.f;
  const float* ip = in + y * 128 + x;
  for (int ci = pt * 32; ci < pt * 32 + 32; ++ci) acc += ip[ci * 16384] * wf[ci];
  part[tid] = acc;
  __syncthreads();
  if (tid < 128) {
    float s = part[tid] + part[tid + 128] + part[tid + 256] + part[tid + 384] + bfp[0];
    part[tid] = fminf(fmaxf(s, -1.f), 1.f);
  }
  __syncthreads();
  if (tid < 64) {
    float m = fmaxf(part[tid], part[tid + 64]);
    for (int off = 32; off; off >>= 1) m = fmaxf(m, __shfl_down(m, off, 64));
    if (tid == 0) rowm[y] = m;
  }
}

// ---------------- mean over rows -> scalar ----------------
__global__ __launch_bounds__(128) void final_kernel(const float* __restrict__ rowm,
                                                    float* __restrict__ out) {
  int x = threadIdx.x;
  float v = rowm[x];
  for (int off = 32; off; off >>= 1) v += __shfl_down(v, off, 64);
  __shared__ float red[2];
  if ((x & 63) == 0) red[x >> 6] = v;
  __syncthreads();
  if (x == 0) out[0] = (red[0] + red[1]) * (1.f / 128.f);
}

extern "C" void kernel_launch(void* const* d_in, const int* in_sizes, int n_in,
                              void* d_out, int out_size, void* d_ws, size_t ws_size,
                              hipStream_t stream) {
  const float* q  = (const float*)d_in[0];
  const float* t  = (const float*)d_in[1];
  const float* w1 = (const float*)d_in[2];
  const float* b1 = (const float*)d_in[3];
  const float* w2 = (const float*)d_in[4];
  const float* b2 = (const float*)d_in[5];
  const float* w3 = (const float*)d_in[6];
  const float* b3 = (const float*)d_in[7];
  const float* wf = (const float*)d_in[8];
  const float* bf = (const float*)d_in[9];
  float* out = (float*)d_out;
  char* ws = (char*)d_ws;

  unsigned char* qf8 = (unsigned char*)(ws + 0);          // 17,694,720
  unsigned char* tf8 = (unsigned char*)(ws + 17694720);   // 17,694,720
  float* cmax = (float*)(ws + 35389440);                  // 9,437,184
  float* f2f  = (float*)(ws + 44826624);                  // 512x512
  float* x1   = (float*)(ws + 45875200);                  // 32x256x256
  float* x2b  = (float*)(ws + 54263808);                  // 64x128x128
  float* x3   = (float*)(ws + 58458112);                  // 128x128x128
  float* rowm = (float*)(ws + 66846720);                  // 128

  cvt_fp8_kernel<<<8640, 256, 0, stream>>>(q, t, (unsigned int*)qf8, (unsigned int*)tf8, 1105920);
  gemm_cmax_kernel<<<256, 768, 0, stream>>>(qf8, tf8, cmax);
  mean9_kernel<<<512, 512, 0, stream>>>(cmax, f2f);
  conv1_kernel<<<256, 256, 0, stream>>>(f2f, w1, b1, x1);
  conv2_kernel<<<256, 256, 0, stream>>>(x1, w2, b2, x2b);
  conv3_kernel<<<256, 256, 0, stream>>>(x2b, w3, b3, x3);
  convf_kernel<<<128, 512, 0, stream>>>(x3, wf, bf, rowm);
  final_kernel<<<1, 128, 0, stream>>>(rowm, out);
}